// Round 4
// baseline (255.052 us; speedup 1.0000x reference)
//
#include <hip/hip_runtime.h>

typedef _Float16 f16_t;
typedef __fp16 fp16x2 __attribute__((ext_vector_type(2)));
typedef _Float16 f16x2 __attribute__((ext_vector_type(2)));
typedef _Float16 f16x4 __attribute__((ext_vector_type(4)));
typedef _Float16 f16x8 __attribute__((ext_vector_type(8)));
typedef float f32x4 __attribute__((ext_vector_type(4)));

#define D_MODEL 1024
#define LSEQ 4096
#define NH 16
#define DH 64
// (1/sqrt(64)) * log2(e), folded into Wq so scores feed v_exp_f32 (base-2) directly
#define QSCALE 0.18033688011112042f

#define GLDS16(g, l)                                                     \
    __builtin_amdgcn_global_load_lds(                                    \
        (const __attribute__((address_space(1))) void*)(g),              \
        (__attribute__((address_space(3))) void*)(l), 16, 0, 0)

#define WAIT_VM(n) asm volatile("s_waitcnt vmcnt(" #n ")" ::: "memory")

// ---------------- fp32 -> fp16 conversion ----------------
__global__ __launch_bounds__(256) void cvt_x(const float* __restrict__ in,
                                             f16_t* __restrict__ out, int n) {
    int i = (blockIdx.x * 256 + threadIdx.x) * 4;
    if (i + 3 < n) {
        float4 v = *(const float4*)&in[i];
        alignas(8) f16_t o4[4] = {(f16_t)v.x, (f16_t)v.y, (f16_t)v.z, (f16_t)v.w};
        *(uint2*)&out[i] = *(const uint2*)o4;
    }
}

// all 4 weights in one launch; Wq gets QSCALE folded in
__global__ __launch_bounds__(256) void cvt_w4(const float* __restrict__ w0,
                                              const float* __restrict__ w1,
                                              const float* __restrict__ w2,
                                              const float* __restrict__ w3,
                                              f16_t* __restrict__ out) {
    const int q = blockIdx.y;
    const float* src = (q == 0) ? w0 : (q == 1) ? w1 : (q == 2) ? w2 : w3;
    const float scale = (q == 0) ? QSCALE : 1.f;
    int i = (blockIdx.x * 256 + threadIdx.x) * 4;
    float4 v = *(const float4*)&src[i];
    alignas(8) f16_t o4[4] = {(f16_t)(v.x * scale), (f16_t)(v.y * scale),
                              (f16_t)(v.z * scale), (f16_t)(v.w * scale)};
    *(uint2*)&out[(size_t)q * (D_MODEL * D_MODEL) + i] = *(const uint2*)o4;
}

// ---------------- fp16 GEMM: C = A @ B^T (unchanged) ----------------
__global__ __launch_bounds__(256, 3) void gemm_f16(const f16_t* __restrict__ A,
                                                   const f16_t* __restrict__ B,
                                                   void* __restrict__ Cout,
                                                   int M, int N, int K, int mode) {
    __shared__ alignas(16) f16_t As[3][128 * 32];
    __shared__ alignas(16) f16_t Bs[3][128 * 32];

    const int tid  = threadIdx.x;
    const int wave = tid >> 6;
    const int lane = tid & 63;
    const int quad = lane >> 4;
    const int l16  = lane & 15;
    const int wm = (wave & 1) * 64;
    const int wn = (wave >> 1) * 64;
    const int bm = blockIdx.x * 128;
    const int bn = blockIdx.y * 128;

    f32x4 acc[4][4] = {};
    const int nk = K / 32;

    auto stage = [&](int kt, int b) {
        const int c0 = wave * 2;
        GLDS16(&A[(size_t)(bm + c0 * 16 + l16) * K + kt * 32 + quad * 8],
               &As[b][c0 * 512]);
        GLDS16(&A[(size_t)(bm + (c0 + 1) * 16 + l16) * K + kt * 32 + quad * 8],
               &As[b][(c0 + 1) * 512]);
        GLDS16(&B[(size_t)(bn + c0 * 16 + l16) * K + kt * 32 + quad * 8],
               &Bs[b][c0 * 512]);
        GLDS16(&B[(size_t)(bn + (c0 + 1) * 16 + l16) * K + kt * 32 + quad * 8],
               &Bs[b][(c0 + 1) * 512]);
    };

    stage(0, 0);
    stage(1, 1);
    for (int kt = 0; kt < nk; ++kt) {
        const int cb = kt % 3;
        if (kt < nk - 1) WAIT_VM(4);
        else             WAIT_VM(0);
        __syncthreads();
        if (kt + 2 < nk) stage(kt + 2, (kt + 2) % 3);

        f16x8 af[4], bfr[4];
#pragma unroll
        for (int mt = 0; mt < 4; ++mt)
            af[mt] = *(const f16x8*)&As[cb][((wm >> 4) + mt) * 512 + lane * 8];
#pragma unroll
        for (int nt = 0; nt < 4; ++nt)
            bfr[nt] = *(const f16x8*)&Bs[cb][((wn >> 4) + nt) * 512 + lane * 8];
#pragma unroll
        for (int mt = 0; mt < 4; ++mt)
#pragma unroll
            for (int nt = 0; nt < 4; ++nt)
                acc[mt][nt] = __builtin_amdgcn_mfma_f32_16x16x32_f16(
                    bfr[nt], af[mt], acc[mt][nt], 0, 0, 0);
    }

#pragma unroll
    for (int mt = 0; mt < 4; ++mt)
#pragma unroll
        for (int nt = 0; nt < 4; ++nt) {
            int row = bm + wm + mt * 16 + l16;
            int col = bn + wn + nt * 16 + quad * 4;
            if (mode == 0) {
                f16x4 p = {(f16_t)acc[mt][nt][0], (f16_t)acc[mt][nt][1],
                           (f16_t)acc[mt][nt][2], (f16_t)acc[mt][nt][3]};
                *(f16x4*)&((f16_t*)Cout)[((size_t)(col >> 6) * M + row) * 64 +
                                         (col & 63)] = p;
            } else {
                *(f32x4*)&((float*)Cout)[(size_t)row * N + col] = acc[mt][nt];
            }
        }
}

// ---------------- V fragmenting: vh[H][L][64] -> v4 (x32 A-operand image) ----
// Per head, per 64-key tile lt: 8 chunks (c8 = mtp*4 + dt) of 512 f16, one
// 16x32 x32-MFMA A-fragment each.  Fragment element (lane = g*16 + l16, j):
//   d   = dt*16 + l16
//   key = lt*64 + mtp*32 + kappa(g, j),  kappa(g,j) = j<4 ? 4g+j : 16+4g+(j-4)
// kappa matches the natural register packing of two exp'd 16-key S^T tiles
// (tile0 regs -> j=0..3, tile1 regs -> j=4..7), so in attn the exp'd scores
// feed a full-rate 16x16x32 PV MFMA straight from registers: no shuffles,
// no P LDS round-trip.
__global__ __launch_bounds__(256) void transpose_v(const f16_t* __restrict__ vh,
                                                   f16_t* __restrict__ v4) {
    __shared__ f16_t Ts[64][72];
    const int t = threadIdx.x;
    const int lt = blockIdx.x;
    const int head = blockIdx.y;

#pragma unroll
    for (int i = 0; i < 2; ++i) {
        int idx = t + i * 256;
        int row = idx >> 3, part = idx & 7;
        *(uint4*)&Ts[row][part * 8] =
            *(const uint4*)&vh[((size_t)head * LSEQ + lt * 64 + row) * DH + part * 8];
    }
    __syncthreads();

    const int c8  = t >> 5;          // chunk 0..7
    const int mtp = c8 >> 2, dt = c8 & 3;
    const int l0  = (t & 31) * 2;    // two lanes per thread
    alignas(16) f16_t buf[16];
#pragma unroll
    for (int li = 0; li < 2; ++li) {
        const int l = l0 + li;
        const int g = l >> 4, l16 = l & 15;
#pragma unroll
        for (int j = 0; j < 8; ++j) {
            int key = mtp * 32 + (j < 4 ? 4 * g + j : 16 + 4 * g + (j - 4));
            buf[li * 8 + j] = Ts[key][dt * 16 + l16];
        }
    }
    f16_t* dst = v4 + (size_t)head * (LSEQ * DH) + (size_t)lt * 4096 + c8 * 512 + l0 * 8;
    *(uint4*)&dst[0] = *(const uint4*)&buf[0];
    *(uint4*)&dst[8] = *(const uint4*)&buf[8];
}

// ---------------- attention ----------------
// qh/kh: [NH][L][64] f16 (Q pre-scaled), v4: fragmented V (above), ao: [L][1024]
// Barrier-free main loop: each of 8 waves (4 q-panels x 2 key-halves) is
// self-sufficient.  K tiles stream through a PRIVATE double-buffered 16KB LDS
// slice via global_load_lds (wave-uniform dest, no cross-wave consumer -> no
// __syncthreads in the loop); V streams straight to registers (the kappa image
// is lane-contiguous).  K staging uses PRE-SWIZZLED per-lane global source
// addresses (fragment order) with a linear LDS dest — rule #21: the source
// permutation must BE the fragment permutation (R3's linear memcpy was the
// correctness bug).  The K prefetch stays in flight across the whole compute
// phase; L1 absorbs the 4-way wq re-read of K/V.
__global__ __launch_bounds__(512, 2) void attn_kernel(const f16_t* __restrict__ qh,
                                                      const f16_t* __restrict__ kh,
                                                      const f16_t* __restrict__ v4,
                                                      f16_t* __restrict__ ao) {
    __shared__ alignas(16) f16_t Ksm[8 * 8192];   // 128KB: per-wave dbuf K tiles
    __shared__ alignas(16) float lscr[16 * 64];   // 4KB
    const int tid  = threadIdx.x;
    const int wave = tid >> 6;        // 0..7
    const int lane = tid & 63;
    const int quad = lane >> 4;
    const int l16  = lane & 15;
    const int wq   = wave & 3;        // q sub-panel
    const int kha  = wave >> 2;       // key half

    const int id = blockIdx.x;
    const int head = id & 15;         // blocks of a head share an XCD (head%8)
    const int qrow0 = (id >> 4) * 256 + wq * 64;

    const f16_t* Q   = qh + (size_t)head * LSEQ * DH;
    const f16_t* K   = kh + (size_t)head * LSEQ * DH + (size_t)kha * (LSEQ / 2) * DH;
    const f16_t* V4h = v4 + (size_t)head * LSEQ * DH + (size_t)kha * (LSEQ / 2) * DH;
    f16_t* kpriv = Ksm + wave * 8192;  // [2 buf][4096 f16]

    f16x8 qf[4][2];
#pragma unroll
    for (int qt = 0; qt < 4; ++qt)
#pragma unroll
        for (int kc = 0; kc < 2; ++kc)
            qf[qt][kc] = *(const f16x8*)
                &Q[(size_t)(qrow0 + qt * 16 + l16) * DH + kc * 32 + quad * 8];

    f32x4 o[4][4] = {};
    float lp[4] = {0.f, 0.f, 0.f, 0.f};

    // prologue: K(0) -> buf0, fragment-ordered source (chunk c: mt=c>>1, kc=c&1)
#pragma unroll
    for (int c = 0; c < 8; ++c)
        GLDS16(&K[(size_t)((c >> 1) * 16 + l16) * DH + (c & 1) * 32 + quad * 8],
               &kpriv[c * 512]);

    const int NT = LSEQ / 2 / 64;  // 32 tiles per half
    for (int kt = 0; kt < NT; ++kt) {
        const int cb = kt & 1;
        const f16_t* ks = kpriv + cb * 4096;

        WAIT_VM(0);  // K(kt) landed in buf cb (issued a full iteration ago)

        // V(kt) -> registers (kappa image is a pure lane-contiguous memcpy);
        // compiler inserts the counted vmcnt before PV use.
        f16x8 vf[8];
#pragma unroll
        for (int c = 0; c < 8; ++c)
            vf[c] = *(const f16x8*)&V4h[(size_t)kt * 4096 + c * 512 + lane * 8];
        __builtin_amdgcn_sched_barrier(0);  // keep vf issue BEFORE the GLDS below

        // prefetch K(kt+1) -> other buffer; stays in flight across compute
        if (kt + 1 < NT) {
            const f16_t* kn = K + (size_t)(kt + 1) * 64 * DH;
            f16_t* kd = kpriv + (cb ^ 1) * 4096;
#pragma unroll
            for (int c = 0; c < 8; ++c)
                GLDS16(&kn[(size_t)((c >> 1) * 16 + l16) * DH + (c & 1) * 32 + quad * 8],
                       &kd[c * 512]);
        }

#pragma unroll
        for (int mtp = 0; mtp < 2; ++mtp) {
            // K fragments for this 32-key block (chunks mtp*4 .. mtp*4+3)
            f16x8 kf[4];
#pragma unroll
            for (int c = 0; c < 4; ++c)
                kf[c] = *(const f16x8*)&ks[(mtp * 4 + c) * 512 + lane * 8];

            // S^T: two 16-key sub-tiles kept in separate regs
            f32x4 s[2][4] = {};
#pragma unroll
            for (int h = 0; h < 2; ++h) {
#pragma unroll
                for (int qt = 0; qt < 4; ++qt) {
                    s[h][qt] = __builtin_amdgcn_mfma_f32_16x16x32_f16(
                        kf[h * 2 + 0], qf[qt][0], s[h][qt], 0, 0, 0);
                    s[h][qt] = __builtin_amdgcn_mfma_f32_16x16x32_f16(
                        kf[h * 2 + 1], qf[qt][1], s[h][qt], 0, 0, 0);
                }
            }

#pragma unroll
            for (int qt = 0; qt < 4; ++qt) {
                float e0 = __builtin_amdgcn_exp2f(s[0][qt][0]);
                float e1 = __builtin_amdgcn_exp2f(s[0][qt][1]);
                float e2 = __builtin_amdgcn_exp2f(s[0][qt][2]);
                float e3 = __builtin_amdgcn_exp2f(s[0][qt][3]);
                float e4 = __builtin_amdgcn_exp2f(s[1][qt][0]);
                float e5 = __builtin_amdgcn_exp2f(s[1][qt][1]);
                float e6 = __builtin_amdgcn_exp2f(s[1][qt][2]);
                float e7 = __builtin_amdgcn_exp2f(s[1][qt][3]);
                lp[qt] += ((e0 + e1) + (e2 + e3)) + ((e4 + e5) + (e6 + e7));
                fp16x2 p01 = __builtin_amdgcn_cvt_pkrtz(e0, e1);
                fp16x2 p23 = __builtin_amdgcn_cvt_pkrtz(e2, e3);
                fp16x2 p45 = __builtin_amdgcn_cvt_pkrtz(e4, e5);
                fp16x2 p67 = __builtin_amdgcn_cvt_pkrtz(e6, e7);
                f16x8 p = {__builtin_bit_cast(f16x2, p01)[0],
                           __builtin_bit_cast(f16x2, p01)[1],
                           __builtin_bit_cast(f16x2, p23)[0],
                           __builtin_bit_cast(f16x2, p23)[1],
                           __builtin_bit_cast(f16x2, p45)[0],
                           __builtin_bit_cast(f16x2, p45)[1],
                           __builtin_bit_cast(f16x2, p67)[0],
                           __builtin_bit_cast(f16x2, p67)[1]};
                // O^T += V^T . P^T : full-rate x32 MFMA, A=vf from registers
#pragma unroll
                for (int dt = 0; dt < 4; ++dt)
                    o[dt][qt] = __builtin_amdgcn_mfma_f32_16x16x32_f16(
                        vf[mtp * 4 + dt], p, o[dt][qt], 0, 0, 0);
            }
        }
    }

    // ---- merge the two key-halves (pure sums) ----
    WAIT_VM(0);          // no GLDS in flight before Ksm is reused as scratch
    __syncthreads();
    float* scr = (float*)Ksm;   // 64 KB used
    if (wave >= 4) {
#pragma unroll
        for (int dt = 0; dt < 4; ++dt)
#pragma unroll
            for (int qt = 0; qt < 4; ++qt)
                *(f32x4*)&scr[(((wave - 4) * 16 + dt * 4 + qt) * 64 + lane) * 4] =
                    o[dt][qt];
#pragma unroll
        for (int qt = 0; qt < 4; ++qt)
            lscr[((wave - 4) * 4 + qt) * 64 + lane] = lp[qt];
    }
    __syncthreads();
    if (wave < 4) {
#pragma unroll
        for (int dt = 0; dt < 4; ++dt)
#pragma unroll
            for (int qt = 0; qt < 4; ++qt)
                o[dt][qt] += *(const f32x4*)
                    &scr[((wave * 16 + dt * 4 + qt) * 64 + lane) * 4];
#pragma unroll
        for (int qt = 0; qt < 4; ++qt) {
            float t = lp[qt] + lscr[(wave * 4 + qt) * 64 + lane];
            t += __shfl_xor(t, 16, 64);
            t += __shfl_xor(t, 32, 64);
            lp[qt] = 1.f / t;
        }
#pragma unroll
        for (int dt = 0; dt < 4; ++dt)
#pragma unroll
            for (int qt = 0; qt < 4; ++qt) {
                f16x4 ov = {(f16_t)(o[dt][qt][0] * lp[qt]),
                            (f16_t)(o[dt][qt][1] * lp[qt]),
                            (f16_t)(o[dt][qt][2] * lp[qt]),
                            (f16_t)(o[dt][qt][3] * lp[qt])};
                int qrow = qrow0 + qt * 16 + l16;
                *(f16x4*)&ao[(size_t)qrow * D_MODEL + head * 64 + dt * 16 +
                             quad * 4] = ov;
            }
    }
}

extern "C" void kernel_launch(void* const* d_in, const int* in_sizes, int n_in,
                              void* d_out, int out_size, void* d_ws, size_t ws_size,
                              hipStream_t stream) {
    const float* x  = (const float*)d_in[0];
    const float* Wq = (const float*)d_in[1];
    const float* Wk = (const float*)d_in[2];
    const float* Wv = (const float*)d_in[3];
    const float* Wo = (const float*)d_in[4];

    f16_t* xb = (f16_t*)d_ws;                        // [4096][1024]
    f16_t* wq = xb + (size_t)LSEQ * D_MODEL;         // [3072][1024] qkv concat
    f16_t* wo = wq + (size_t)3 * D_MODEL * D_MODEL;  // [1024][1024]
    f16_t* qh = wo + (size_t)D_MODEL * D_MODEL;      // [16][4096][64]
    f16_t* kh = qh + (size_t)LSEQ * D_MODEL;
    f16_t* vh = kh + (size_t)LSEQ * D_MODEL;
    f16_t* v4 = vh + (size_t)LSEQ * D_MODEL;         // fragmented V
    f16_t* ao = v4 + (size_t)LSEQ * D_MODEL;         // [4096][1024]

    const int nx = LSEQ * D_MODEL;
    cvt_x<<<nx / 1024, 256, 0, stream>>>(x, xb, nx);
    cvt_w4<<<dim3(D_MODEL * D_MODEL / 1024, 4), 256, 0, stream>>>(Wq, Wk, Wv, Wo, wq);

    gemm_f16<<<dim3(LSEQ / 128, 3 * D_MODEL / 128), 256, 0, stream>>>(
        xb, wq, qh, LSEQ, 3 * D_MODEL, D_MODEL, 0);

    transpose_v<<<dim3(LSEQ / 64, NH), 256, 0, stream>>>(vh, v4);

    attn_kernel<<<dim3((LSEQ / 256) * NH), 512, 0, stream>>>(qh, kh, v4, ao);

    gemm_f16<<<dim3(LSEQ / 128, D_MODEL / 128), 256, 0, stream>>>(
        ao, wo, d_out, LSEQ, D_MODEL, D_MODEL, 1);
}

// Round 5
// 247.001 us; speedup vs baseline: 1.0326x; 1.0326x over previous
//
#include <hip/hip_runtime.h>

typedef _Float16 f16_t;
typedef __fp16 fp16x2 __attribute__((ext_vector_type(2)));
typedef _Float16 f16x2 __attribute__((ext_vector_type(2)));
typedef _Float16 f16x4 __attribute__((ext_vector_type(4)));
typedef _Float16 f16x8 __attribute__((ext_vector_type(8)));
typedef float f32x4 __attribute__((ext_vector_type(4)));

#define D_MODEL 1024
#define LSEQ 4096
#define NH 16
#define DH 64
// (1/sqrt(64)) * log2(e), folded into Wq so scores feed v_exp_f32 (base-2) directly
#define QSCALE 0.18033688011112042f

#define GLDS16(g, l)                                                     \
    __builtin_amdgcn_global_load_lds(                                    \
        (const __attribute__((address_space(1))) void*)(g),              \
        (__attribute__((address_space(3))) void*)(l), 16, 0, 0)

#define WAIT_VM(n) asm volatile("s_waitcnt vmcnt(" #n ")" ::: "memory")

// ---------------- fp32 -> fp16 conversion ----------------
__global__ __launch_bounds__(256) void cvt_x(const float* __restrict__ in,
                                             f16_t* __restrict__ out, int n) {
    int i = (blockIdx.x * 256 + threadIdx.x) * 4;
    if (i + 3 < n) {
        float4 v = *(const float4*)&in[i];
        alignas(8) f16_t o4[4] = {(f16_t)v.x, (f16_t)v.y, (f16_t)v.z, (f16_t)v.w};
        *(uint2*)&out[i] = *(const uint2*)o4;
    }
}

// all 4 weights in one launch; Wq gets QSCALE folded in
__global__ __launch_bounds__(256) void cvt_w4(const float* __restrict__ w0,
                                              const float* __restrict__ w1,
                                              const float* __restrict__ w2,
                                              const float* __restrict__ w3,
                                              f16_t* __restrict__ out) {
    const int q = blockIdx.y;
    const float* src = (q == 0) ? w0 : (q == 1) ? w1 : (q == 2) ? w2 : w3;
    const float scale = (q == 0) ? QSCALE : 1.f;
    int i = (blockIdx.x * 256 + threadIdx.x) * 4;
    float4 v = *(const float4*)&src[i];
    alignas(8) f16_t o4[4] = {(f16_t)(v.x * scale), (f16_t)(v.y * scale),
                              (f16_t)(v.z * scale), (f16_t)(v.w * scale)};
    *(uint2*)&out[(size_t)q * (D_MODEL * D_MODEL) + i] = *(const uint2*)o4;
}

// ---------------- fp16 GEMM: C = A @ B^T (unchanged) ----------------
__global__ __launch_bounds__(256, 3) void gemm_f16(const f16_t* __restrict__ A,
                                                   const f16_t* __restrict__ B,
                                                   void* __restrict__ Cout,
                                                   int M, int N, int K, int mode) {
    __shared__ alignas(16) f16_t As[3][128 * 32];
    __shared__ alignas(16) f16_t Bs[3][128 * 32];

    const int tid  = threadIdx.x;
    const int wave = tid >> 6;
    const int lane = tid & 63;
    const int quad = lane >> 4;
    const int l16  = lane & 15;
    const int wm = (wave & 1) * 64;
    const int wn = (wave >> 1) * 64;
    const int bm = blockIdx.x * 128;
    const int bn = blockIdx.y * 128;

    f32x4 acc[4][4] = {};
    const int nk = K / 32;

    auto stage = [&](int kt, int b) {
        const int c0 = wave * 2;
        GLDS16(&A[(size_t)(bm + c0 * 16 + l16) * K + kt * 32 + quad * 8],
               &As[b][c0 * 512]);
        GLDS16(&A[(size_t)(bm + (c0 + 1) * 16 + l16) * K + kt * 32 + quad * 8],
               &As[b][(c0 + 1) * 512]);
        GLDS16(&B[(size_t)(bn + c0 * 16 + l16) * K + kt * 32 + quad * 8],
               &Bs[b][c0 * 512]);
        GLDS16(&B[(size_t)(bn + (c0 + 1) * 16 + l16) * K + kt * 32 + quad * 8],
               &Bs[b][(c0 + 1) * 512]);
    };

    stage(0, 0);
    stage(1, 1);
    for (int kt = 0; kt < nk; ++kt) {
        const int cb = kt % 3;
        if (kt < nk - 1) WAIT_VM(4);
        else             WAIT_VM(0);
        __syncthreads();
        if (kt + 2 < nk) stage(kt + 2, (kt + 2) % 3);

        f16x8 af[4], bfr[4];
#pragma unroll
        for (int mt = 0; mt < 4; ++mt)
            af[mt] = *(const f16x8*)&As[cb][((wm >> 4) + mt) * 512 + lane * 8];
#pragma unroll
        for (int nt = 0; nt < 4; ++nt)
            bfr[nt] = *(const f16x8*)&Bs[cb][((wn >> 4) + nt) * 512 + lane * 8];
#pragma unroll
        for (int mt = 0; mt < 4; ++mt)
#pragma unroll
            for (int nt = 0; nt < 4; ++nt)
                acc[mt][nt] = __builtin_amdgcn_mfma_f32_16x16x32_f16(
                    bfr[nt], af[mt], acc[mt][nt], 0, 0, 0);
    }

#pragma unroll
    for (int mt = 0; mt < 4; ++mt)
#pragma unroll
        for (int nt = 0; nt < 4; ++nt) {
            int row = bm + wm + mt * 16 + l16;
            int col = bn + wn + nt * 16 + quad * 4;
            if (mode == 0) {
                f16x4 p = {(f16_t)acc[mt][nt][0], (f16_t)acc[mt][nt][1],
                           (f16_t)acc[mt][nt][2], (f16_t)acc[mt][nt][3]};
                *(f16x4*)&((f16_t*)Cout)[((size_t)(col >> 6) * M + row) * 64 +
                                         (col & 63)] = p;
            } else {
                *(f32x4*)&((float*)Cout)[(size_t)row * N + col] = acc[mt][nt];
            }
        }
}

// ---------------- V fragmenting: vh[H][L][64] -> v4 (x32 A-operand image) ----
// Per head, per 64-key tile lt: 8 chunks (c8 = mtp*4 + dt) of 512 f16, one
// 16x32 x32-MFMA A-fragment each.  Fragment element (lane = g*16 + l16, j):
//   d   = dt*16 + l16
//   key = lt*64 + mtp*32 + kappa(g, j),  kappa(g,j) = j<4 ? 4g+j : 16+4g+(j-4)
// kappa matches the natural register packing of two exp'd 16-key S^T tiles
// (tile0 regs -> j=0..3, tile1 regs -> j=4..7), so in attn the exp'd scores
// feed a full-rate 16x16x32 PV MFMA straight from registers: no shuffles,
// no P LDS round-trip.
__global__ __launch_bounds__(256) void transpose_v(const f16_t* __restrict__ vh,
                                                   f16_t* __restrict__ v4) {
    __shared__ f16_t Ts[64][72];
    const int t = threadIdx.x;
    const int lt = blockIdx.x;
    const int head = blockIdx.y;

#pragma unroll
    for (int i = 0; i < 2; ++i) {
        int idx = t + i * 256;
        int row = idx >> 3, part = idx & 7;
        *(uint4*)&Ts[row][part * 8] =
            *(const uint4*)&vh[((size_t)head * LSEQ + lt * 64 + row) * DH + part * 8];
    }
    __syncthreads();

    const int c8  = t >> 5;          // chunk 0..7
    const int mtp = c8 >> 2, dt = c8 & 3;
    const int l0  = (t & 31) * 2;    // two lanes per thread
    alignas(16) f16_t buf[16];
#pragma unroll
    for (int li = 0; li < 2; ++li) {
        const int l = l0 + li;
        const int g = l >> 4, l16 = l & 15;
#pragma unroll
        for (int j = 0; j < 8; ++j) {
            int key = mtp * 32 + (j < 4 ? 4 * g + j : 16 + 4 * g + (j - 4));
            buf[li * 8 + j] = Ts[key][dt * 16 + l16];
        }
    }
    f16_t* dst = v4 + (size_t)head * (LSEQ * DH) + (size_t)lt * 4096 + c8 * 512 + l0 * 8;
    *(uint4*)&dst[0] = *(const uint4*)&buf[0];
    *(uint4*)&dst[8] = *(const uint4*)&buf[8];
}

// ---------------- attention ----------------
// qh/kh: [NH][L][64] f16 (Q pre-scaled), v4: fragmented V (above), ao: [L][1024]
// 8 waves = 8 independent 16-row q-panels (128-row block, 512 blocks, 2/CU).
// Every wave walks ALL 64 key-tiles; K/V tiles staged cooperatively (each wave
// stages 1 K-chunk + 1 V-chunk = 2 GLDS/iter) into a 3-deep ring with counted
// WAIT_VM(2) -- never drained mid-loop (T4).  No split-K: no merge epilogue,
// each wave reduces its own softmax denominator with 2 shfl_xors and writes.
// K staging uses fragment-ordered per-lane global sources (rule #21).
__global__ __launch_bounds__(512, 4) void attn_kernel(const f16_t* __restrict__ qh,
                                                      const f16_t* __restrict__ kh,
                                                      const f16_t* __restrict__ v4,
                                                      f16_t* __restrict__ ao) {
    __shared__ alignas(16) f16_t Ks[3][4096];   // 24KB: 3-deep K tile ring
    __shared__ alignas(16) f16_t Vs[3][4096];   // 24KB: 3-deep V tile ring

    const int tid  = threadIdx.x;
    const int wave = tid >> 6;        // 0..7 : q sub-panel
    const int lane = tid & 63;
    const int quad = lane >> 4;
    const int l16  = lane & 15;

    const int id = blockIdx.x;
    const int head = id & 15;         // blocks of a head share an XCD (head%8)
    const int qrow0 = (id >> 4) * 128 + wave * 16;

    const f16_t* Q   = qh + (size_t)head * LSEQ * DH;
    const f16_t* K   = kh + (size_t)head * LSEQ * DH;
    const f16_t* V4h = v4 + (size_t)head * LSEQ * DH;

    f16x8 qf[2];
#pragma unroll
    for (int kc = 0; kc < 2; ++kc)
        qf[kc] = *(const f16x8*)
            &Q[(size_t)(qrow0 + l16) * DH + kc * 32 + quad * 8];

    f32x4 o[4] = {};
    float lp = 0.f;

    // wave w stages K chunk w (fragment-ordered source: mt=w>>1, kc=w&1) and
    // V chunk w (linear memcpy of the kappa image) of tile kt -> 2 GLDS/wave.
    auto stage = [&](int kt, int b) {
        const int c = wave;
        GLDS16(&K[(size_t)(kt * 64 + (c >> 1) * 16 + l16) * DH + (c & 1) * 32 + quad * 8],
               &Ks[b][c * 512]);
        GLDS16(&V4h[(size_t)kt * 4096 + c * 512 + lane * 8],
               &Vs[b][c * 512]);
    };

    stage(0, 0);
    stage(1, 1);

    const int NT = LSEQ / 64;  // 64 tiles
    for (int kt = 0; kt < NT; ++kt) {
        const int cb = kt % 3;
        if (kt < NT - 1) WAIT_VM(2);   // tile kt landed; kt+1 stays in flight
        else             WAIT_VM(0);
        __syncthreads();
        if (kt + 2 < NT) stage(kt + 2, (kt + 2) % 3);

        const f16_t* ks = Ks[cb];
        const f16_t* vs = Vs[cb];

        __builtin_amdgcn_s_setprio(1);
#pragma unroll
        for (int mtp = 0; mtp < 2; ++mtp) {
            // S^T for a 32-key block: two 16-key sub-tiles in separate regs
            f32x4 s[2] = {};
#pragma unroll
            for (int h = 0; h < 2; ++h) {
                const int mt = mtp * 2 + h;
                f16x8 kf0 = *(const f16x8*)&ks[(mt * 2 + 0) * 512 + lane * 8];
                f16x8 kf1 = *(const f16x8*)&ks[(mt * 2 + 1) * 512 + lane * 8];
                s[h] = __builtin_amdgcn_mfma_f32_16x16x32_f16(kf0, qf[0],
                                                              s[h], 0, 0, 0);
                s[h] = __builtin_amdgcn_mfma_f32_16x16x32_f16(kf1, qf[1],
                                                              s[h], 0, 0, 0);
            }

            float e0 = __builtin_amdgcn_exp2f(s[0][0]);
            float e1 = __builtin_amdgcn_exp2f(s[0][1]);
            float e2 = __builtin_amdgcn_exp2f(s[0][2]);
            float e3 = __builtin_amdgcn_exp2f(s[0][3]);
            float e4 = __builtin_amdgcn_exp2f(s[1][0]);
            float e5 = __builtin_amdgcn_exp2f(s[1][1]);
            float e6 = __builtin_amdgcn_exp2f(s[1][2]);
            float e7 = __builtin_amdgcn_exp2f(s[1][3]);
            lp += ((e0 + e1) + (e2 + e3)) + ((e4 + e5) + (e6 + e7));
            fp16x2 p01 = __builtin_amdgcn_cvt_pkrtz(e0, e1);
            fp16x2 p23 = __builtin_amdgcn_cvt_pkrtz(e2, e3);
            fp16x2 p45 = __builtin_amdgcn_cvt_pkrtz(e4, e5);
            fp16x2 p67 = __builtin_amdgcn_cvt_pkrtz(e6, e7);
            f16x8 p = {__builtin_bit_cast(f16x2, p01)[0],
                       __builtin_bit_cast(f16x2, p01)[1],
                       __builtin_bit_cast(f16x2, p23)[0],
                       __builtin_bit_cast(f16x2, p23)[1],
                       __builtin_bit_cast(f16x2, p45)[0],
                       __builtin_bit_cast(f16x2, p45)[1],
                       __builtin_bit_cast(f16x2, p67)[0],
                       __builtin_bit_cast(f16x2, p67)[1]};

            // V^T x32 A-fragments (kappa-permuted image), O^T += V^T . P^T
#pragma unroll
            for (int dt = 0; dt < 4; ++dt) {
                f16x8 vfd = *(const f16x8*)&vs[(mtp * 4 + dt) * 512 + lane * 8];
                o[dt] = __builtin_amdgcn_mfma_f32_16x16x32_f16(vfd, p,
                                                               o[dt], 0, 0, 0);
            }
        }
        __builtin_amdgcn_s_setprio(0);
    }

    // ---- per-wave epilogue: denom reduce across quads, scale, write ----
    float t = lp;
    t += __shfl_xor(t, 16, 64);
    t += __shfl_xor(t, 32, 64);
    const float r = 1.f / t;
#pragma unroll
    for (int dt = 0; dt < 4; ++dt) {
        f16x4 ov = {(f16_t)(o[dt][0] * r), (f16_t)(o[dt][1] * r),
                    (f16_t)(o[dt][2] * r), (f16_t)(o[dt][3] * r)};
        *(f16x4*)&ao[(size_t)(qrow0 + l16) * D_MODEL + head * 64 + dt * 16 +
                     quad * 4] = ov;
    }
}

extern "C" void kernel_launch(void* const* d_in, const int* in_sizes, int n_in,
                              void* d_out, int out_size, void* d_ws, size_t ws_size,
                              hipStream_t stream) {
    const float* x  = (const float*)d_in[0];
    const float* Wq = (const float*)d_in[1];
    const float* Wk = (const float*)d_in[2];
    const float* Wv = (const float*)d_in[3];
    const float* Wo = (const float*)d_in[4];

    f16_t* xb = (f16_t*)d_ws;                        // [4096][1024]
    f16_t* wq = xb + (size_t)LSEQ * D_MODEL;         // [3072][1024] qkv concat
    f16_t* wo = wq + (size_t)3 * D_MODEL * D_MODEL;  // [1024][1024]
    f16_t* qh = wo + (size_t)D_MODEL * D_MODEL;      // [16][4096][64]
    f16_t* kh = qh + (size_t)LSEQ * D_MODEL;
    f16_t* vh = kh + (size_t)LSEQ * D_MODEL;
    f16_t* v4 = vh + (size_t)LSEQ * D_MODEL;         // fragmented V
    f16_t* ao = v4 + (size_t)LSEQ * D_MODEL;         // [4096][1024]

    const int nx = LSEQ * D_MODEL;
    cvt_x<<<nx / 1024, 256, 0, stream>>>(x, xb, nx);
    cvt_w4<<<dim3(D_MODEL * D_MODEL / 1024, 4), 256, 0, stream>>>(Wq, Wk, Wv, Wo, wq);

    gemm_f16<<<dim3(LSEQ / 128, 3 * D_MODEL / 128), 256, 0, stream>>>(
        xb, wq, qh, LSEQ, 3 * D_MODEL, D_MODEL, 0);

    transpose_v<<<dim3(LSEQ / 64, NH), 256, 0, stream>>>(vh, v4);

    attn_kernel<<<dim3((LSEQ / 128) * NH), 512, 0, stream>>>(qh, kh, v4, ao);

    gemm_f16<<<dim3(LSEQ / 128, D_MODEL / 128), 256, 0, stream>>>(
        ao, wo, d_out, LSEQ, D_MODEL, D_MODEL, 1);
}

// Round 6
// 244.479 us; speedup vs baseline: 1.0432x; 1.0103x over previous
//
#include <hip/hip_runtime.h>

typedef _Float16 f16_t;
typedef __fp16 fp16x2 __attribute__((ext_vector_type(2)));
typedef _Float16 f16x2 __attribute__((ext_vector_type(2)));
typedef _Float16 f16x4 __attribute__((ext_vector_type(4)));
typedef _Float16 f16x8 __attribute__((ext_vector_type(8)));
typedef float f32x4 __attribute__((ext_vector_type(4)));

#define D_MODEL 1024
#define LSEQ 4096
#define NH 16
#define DH 64
// (1/sqrt(64)) * log2(e), folded into Wq so scores feed v_exp_f32 (base-2) directly
#define QSCALE 0.18033688011112042f

#define GLDS16(g, l)                                                     \
    __builtin_amdgcn_global_load_lds(                                    \
        (const __attribute__((address_space(1))) void*)(g),              \
        (__attribute__((address_space(3))) void*)(l), 16, 0, 0)

#define WAIT_VM(n) asm volatile("s_waitcnt vmcnt(" #n ")" ::: "memory")

// ---------------- fp32 -> fp16 conversion ----------------
__global__ __launch_bounds__(256) void cvt_x(const float* __restrict__ in,
                                             f16_t* __restrict__ out, int n) {
    int i = (blockIdx.x * 256 + threadIdx.x) * 4;
    if (i + 3 < n) {
        float4 v = *(const float4*)&in[i];
        alignas(8) f16_t o4[4] = {(f16_t)v.x, (f16_t)v.y, (f16_t)v.z, (f16_t)v.w};
        *(uint2*)&out[i] = *(const uint2*)o4;
    }
}

// all 4 weights in one launch; Wq gets QSCALE folded in
__global__ __launch_bounds__(256) void cvt_w4(const float* __restrict__ w0,
                                              const float* __restrict__ w1,
                                              const float* __restrict__ w2,
                                              const float* __restrict__ w3,
                                              f16_t* __restrict__ out) {
    const int q = blockIdx.y;
    const float* src = (q == 0) ? w0 : (q == 1) ? w1 : (q == 2) ? w2 : w3;
    const float scale = (q == 0) ? QSCALE : 1.f;
    int i = (blockIdx.x * 256 + threadIdx.x) * 4;
    float4 v = *(const float4*)&src[i];
    alignas(8) f16_t o4[4] = {(f16_t)(v.x * scale), (f16_t)(v.y * scale),
                              (f16_t)(v.z * scale), (f16_t)(v.w * scale)};
    *(uint2*)&out[(size_t)q * (D_MODEL * D_MODEL) + i] = *(const uint2*)o4;
}

// ---------------- fp16 GEMM: C = A @ B^T (unchanged) ----------------
__global__ __launch_bounds__(256, 3) void gemm_f16(const f16_t* __restrict__ A,
                                                   const f16_t* __restrict__ B,
                                                   void* __restrict__ Cout,
                                                   int M, int N, int K, int mode) {
    __shared__ alignas(16) f16_t As[3][128 * 32];
    __shared__ alignas(16) f16_t Bs[3][128 * 32];

    const int tid  = threadIdx.x;
    const int wave = tid >> 6;
    const int lane = tid & 63;
    const int quad = lane >> 4;
    const int l16  = lane & 15;
    const int wm = (wave & 1) * 64;
    const int wn = (wave >> 1) * 64;
    const int bm = blockIdx.x * 128;
    const int bn = blockIdx.y * 128;

    f32x4 acc[4][4] = {};
    const int nk = K / 32;

    auto stage = [&](int kt, int b) {
        const int c0 = wave * 2;
        GLDS16(&A[(size_t)(bm + c0 * 16 + l16) * K + kt * 32 + quad * 8],
               &As[b][c0 * 512]);
        GLDS16(&A[(size_t)(bm + (c0 + 1) * 16 + l16) * K + kt * 32 + quad * 8],
               &As[b][(c0 + 1) * 512]);
        GLDS16(&B[(size_t)(bn + c0 * 16 + l16) * K + kt * 32 + quad * 8],
               &Bs[b][c0 * 512]);
        GLDS16(&B[(size_t)(bn + (c0 + 1) * 16 + l16) * K + kt * 32 + quad * 8],
               &Bs[b][(c0 + 1) * 512]);
    };

    stage(0, 0);
    stage(1, 1);
    for (int kt = 0; kt < nk; ++kt) {
        const int cb = kt % 3;
        if (kt < nk - 1) WAIT_VM(4);
        else             WAIT_VM(0);
        __syncthreads();
        if (kt + 2 < nk) stage(kt + 2, (kt + 2) % 3);

        f16x8 af[4], bfr[4];
#pragma unroll
        for (int mt = 0; mt < 4; ++mt)
            af[mt] = *(const f16x8*)&As[cb][((wm >> 4) + mt) * 512 + lane * 8];
#pragma unroll
        for (int nt = 0; nt < 4; ++nt)
            bfr[nt] = *(const f16x8*)&Bs[cb][((wn >> 4) + nt) * 512 + lane * 8];
#pragma unroll
        for (int mt = 0; mt < 4; ++mt)
#pragma unroll
            for (int nt = 0; nt < 4; ++nt)
                acc[mt][nt] = __builtin_amdgcn_mfma_f32_16x16x32_f16(
                    bfr[nt], af[mt], acc[mt][nt], 0, 0, 0);
    }

#pragma unroll
    for (int mt = 0; mt < 4; ++mt)
#pragma unroll
        for (int nt = 0; nt < 4; ++nt) {
            int row = bm + wm + mt * 16 + l16;
            int col = bn + wn + nt * 16 + quad * 4;
            if (mode == 0) {
                f16x4 p = {(f16_t)acc[mt][nt][0], (f16_t)acc[mt][nt][1],
                           (f16_t)acc[mt][nt][2], (f16_t)acc[mt][nt][3]};
                *(f16x4*)&((f16_t*)Cout)[((size_t)(col >> 6) * M + row) * 64 +
                                         (col & 63)] = p;
            } else {
                *(f32x4*)&((float*)Cout)[(size_t)row * N + col] = acc[mt][nt];
            }
        }
}

// ---------------- V fragmenting: vh[H][L][64] -> v4 (x32 A-operand image) ----
// Per head, per 64-key tile lt: 8 chunks (c8 = mtp*4 + dt) of 512 f16, one
// 16x32 x32-MFMA A-fragment each.  Fragment element (lane = g*16 + l16, j):
//   d   = dt*16 + l16
//   key = lt*64 + mtp*32 + kappa(g, j),  kappa(g,j) = j<4 ? 4g+j : 16+4g+(j-4)
// kappa matches the natural register packing of two exp'd 16-key S^T tiles
// (tile0 regs -> j=0..3, tile1 regs -> j=4..7), so in attn the exp'd scores
// feed a full-rate 16x16x32 PV MFMA straight from registers: no shuffles,
// no P LDS round-trip.
__global__ __launch_bounds__(256) void transpose_v(const f16_t* __restrict__ vh,
                                                   f16_t* __restrict__ v4) {
    __shared__ f16_t Ts[64][72];
    const int t = threadIdx.x;
    const int lt = blockIdx.x;
    const int head = blockIdx.y;

#pragma unroll
    for (int i = 0; i < 2; ++i) {
        int idx = t + i * 256;
        int row = idx >> 3, part = idx & 7;
        *(uint4*)&Ts[row][part * 8] =
            *(const uint4*)&vh[((size_t)head * LSEQ + lt * 64 + row) * DH + part * 8];
    }
    __syncthreads();

    const int c8  = t >> 5;          // chunk 0..7
    const int mtp = c8 >> 2, dt = c8 & 3;
    const int l0  = (t & 31) * 2;    // two lanes per thread
    alignas(16) f16_t buf[16];
#pragma unroll
    for (int li = 0; li < 2; ++li) {
        const int l = l0 + li;
        const int g = l >> 4, l16 = l & 15;
#pragma unroll
        for (int j = 0; j < 8; ++j) {
            int key = mtp * 32 + (j < 4 ? 4 * g + j : 16 + 4 * g + (j - 4));
            buf[li * 8 + j] = Ts[key][dt * 16 + l16];
        }
    }
    f16_t* dst = v4 + (size_t)head * (LSEQ * DH) + (size_t)lt * 4096 + c8 * 512 + l0 * 8;
    *(uint4*)&dst[0] = *(const uint4*)&buf[0];
    *(uint4*)&dst[8] = *(const uint4*)&buf[8];
}

// ---------------- attention ----------------
// qh/kh: [NH][L][64] f16 (Q pre-scaled), v4: fragmented V (above), ao: [L][1024]
// R2 structure (8 waves: 4 q-panels x 2 key-halves, 128-row block, 2 blocks/CU)
// with the inner loop SOFTWARE-PIPELINED at mtp granularity to break pipe
// phase-lock: QK(mtp0) and QK(mtp1) are both issued BEFORE softmax(mtp0), so
// the MFMA pipe drains QK-B while the VALU runs softmax-A, and PV-A overlaps
// softmax-B.  Per-wave pipe demand is mixed at every point instead of coarse
// serialized [MFMA][VALU][MFMA] phases.
__global__ __launch_bounds__(512, 4) void attn_kernel(const f16_t* __restrict__ qh,
                                                      const f16_t* __restrict__ kh,
                                                      const f16_t* __restrict__ v4,
                                                      f16_t* __restrict__ ao) {
    // smem: Ks = [0,16K) f16, Vs = [16K,32K) f16; merge reuses as f32 scratch
    __shared__ alignas(16) f16_t smem[32768];
    __shared__ alignas(16) float lscr[8 * 64];
    f16_t* KsB = smem;          // [kha][buf][4096]
    f16_t* VsB = smem + 16384;  // [kha][buf][4096]

    const int tid  = threadIdx.x;
    const int wave = tid >> 6;        // 0..7
    const int lane = tid & 63;
    const int quad = lane >> 4;
    const int l16  = lane & 15;
    const int wq   = wave & 3;        // q sub-panel
    const int kha  = wave >> 2;       // key half

    const int id = blockIdx.x;
    const int head = id & 15;         // blocks of a head share an XCD (head%8)
    const int qrow0 = (id >> 4) * 128 + wq * 32;

    const f16_t* Q  = qh + (size_t)head * LSEQ * DH;
    const f16_t* K  = kh + (size_t)head * LSEQ * DH;
    const f16_t* V4 = v4 + (size_t)head * (LSEQ * DH);

    f16x8 qf[2][2];
#pragma unroll
    for (int qt = 0; qt < 2; ++qt)
#pragma unroll
        for (int kc = 0; kc < 2; ++kc)
            qf[qt][kc] = *(const f16x8*)
                &Q[(size_t)(qrow0 + qt * 16 + l16) * DH + kc * 32 + quad * 8];

    f32x4 o[4][2] = {};
    float lp[2] = {0.f, 0.f};

    auto stage = [&](int kt, int b) {  // 4 GLDS per wave
        f16_t* ks = KsB + (kha * 2 + b) * 4096;
        f16_t* vs = VsB + (kha * 2 + b) * 4096;
        const int ktg = kha * 32 + kt;  // global 64-key tile index
#pragma unroll
        for (int jj = 0; jj < 2; ++jj) {
            const int j = wq * 2 + jj;               // K chunk: mt=wq, kc=jj
            GLDS16(&K[(size_t)(ktg * 64 + wq * 16 + l16) * DH + jj * 32 + quad * 8],
                   &ks[j * 512]);
            // V: pure memcpy of the pre-fragmented image
            GLDS16(&V4[(size_t)ktg * 4096 + wq * 1024 + jj * 512 + lane * 8],
                   &vs[wq * 1024 + jj * 512]);
        }
    };

    const int NT = LSEQ / 2 / 64;  // 32 tiles per half
    stage(0, 0);
    for (int kt = 0; kt < NT; ++kt) {
        const int cb = kt & 1;
        WAIT_VM(0);
        __syncthreads();
        if (kt + 1 < NT) stage(kt + 1, cb ^ 1);

        const f16_t* ks = KsB + (kha * 2 + cb) * 4096;
        const f16_t* vs = VsB + (kha * 2 + cb) * 4096;

        // ---- QK for BOTH 32-key blocks up front (pipe-mix enabler) ----
        f32x4 sA[2][2] = {};   // mtp0: [h][qt]
        {
            f16x8 kfA[4];
#pragma unroll
            for (int c = 0; c < 4; ++c)
                kfA[c] = *(const f16x8*)&ks[c * 512 + lane * 8];
#pragma unroll
            for (int h = 0; h < 2; ++h)
#pragma unroll
                for (int qt = 0; qt < 2; ++qt) {
                    sA[h][qt] = __builtin_amdgcn_mfma_f32_16x16x32_f16(
                        kfA[h * 2 + 0], qf[qt][0], sA[h][qt], 0, 0, 0);
                    sA[h][qt] = __builtin_amdgcn_mfma_f32_16x16x32_f16(
                        kfA[h * 2 + 1], qf[qt][1], sA[h][qt], 0, 0, 0);
                }
        }
        f32x4 sB[2][2] = {};   // mtp1: [h][qt]
        {
            f16x8 kfB[4];
#pragma unroll
            for (int c = 0; c < 4; ++c)
                kfB[c] = *(const f16x8*)&ks[(4 + c) * 512 + lane * 8];
#pragma unroll
            for (int h = 0; h < 2; ++h)
#pragma unroll
                for (int qt = 0; qt < 2; ++qt) {
                    sB[h][qt] = __builtin_amdgcn_mfma_f32_16x16x32_f16(
                        kfB[h * 2 + 0], qf[qt][0], sB[h][qt], 0, 0, 0);
                    sB[h][qt] = __builtin_amdgcn_mfma_f32_16x16x32_f16(
                        kfB[h * 2 + 1], qf[qt][1], sB[h][qt], 0, 0, 0);
                }
        }

        // ---- softmax(mtp0) [VALU] overlaps QK-B drain; then PV-A [MFMA]
        //      overlaps softmax(mtp1); then PV-B ----
#pragma unroll
        for (int mtp = 0; mtp < 2; ++mtp) {
            f32x4 (*s)[2] = (mtp == 0) ? sA : sB;

            f16x8 vfd[4];
#pragma unroll
            for (int dt = 0; dt < 4; ++dt)
                vfd[dt] = *(const f16x8*)&vs[(mtp * 4 + dt) * 512 + lane * 8];

#pragma unroll
            for (int qt = 0; qt < 2; ++qt) {
                float e0 = __builtin_amdgcn_exp2f(s[0][qt][0]);
                float e1 = __builtin_amdgcn_exp2f(s[0][qt][1]);
                float e2 = __builtin_amdgcn_exp2f(s[0][qt][2]);
                float e3 = __builtin_amdgcn_exp2f(s[0][qt][3]);
                float e4 = __builtin_amdgcn_exp2f(s[1][qt][0]);
                float e5 = __builtin_amdgcn_exp2f(s[1][qt][1]);
                float e6 = __builtin_amdgcn_exp2f(s[1][qt][2]);
                float e7 = __builtin_amdgcn_exp2f(s[1][qt][3]);
                lp[qt] += ((e0 + e1) + (e2 + e3)) + ((e4 + e5) + (e6 + e7));
                fp16x2 p01 = __builtin_amdgcn_cvt_pkrtz(e0, e1);
                fp16x2 p23 = __builtin_amdgcn_cvt_pkrtz(e2, e3);
                fp16x2 p45 = __builtin_amdgcn_cvt_pkrtz(e4, e5);
                fp16x2 p67 = __builtin_amdgcn_cvt_pkrtz(e6, e7);
                f16x8 p = {__builtin_bit_cast(f16x2, p01)[0],
                           __builtin_bit_cast(f16x2, p01)[1],
                           __builtin_bit_cast(f16x2, p23)[0],
                           __builtin_bit_cast(f16x2, p23)[1],
                           __builtin_bit_cast(f16x2, p45)[0],
                           __builtin_bit_cast(f16x2, p45)[1],
                           __builtin_bit_cast(f16x2, p67)[0],
                           __builtin_bit_cast(f16x2, p67)[1]};
                // O^T += V^T . P^T : full-rate x32 MFMA, B=p straight from regs
#pragma unroll
                for (int dt = 0; dt < 4; ++dt)
                    o[dt][qt] = __builtin_amdgcn_mfma_f32_16x16x32_f16(
                        vfd[dt], p, o[dt][qt], 0, 0, 0);
            }
        }
    }

    // ---- merge the two key-halves (pure sums) ----
    __syncthreads();
    float* scr = (float*)smem;   // 32 KB used
    if (wave >= 4) {
#pragma unroll
        for (int dt = 0; dt < 4; ++dt)
#pragma unroll
            for (int qt = 0; qt < 2; ++qt)
                *(f32x4*)&scr[(((wave - 4) * 8 + dt * 2 + qt) * 64 + lane) * 4] =
                    o[dt][qt];
#pragma unroll
        for (int qt = 0; qt < 2; ++qt)
            lscr[((wave - 4) * 2 + qt) * 64 + lane] = lp[qt];
    }
    __syncthreads();
    if (wave < 4) {
#pragma unroll
        for (int dt = 0; dt < 4; ++dt)
#pragma unroll
            for (int qt = 0; qt < 2; ++qt)
                o[dt][qt] += *(const f32x4*)
                    &scr[((wave * 8 + dt * 2 + qt) * 64 + lane) * 4];
#pragma unroll
        for (int qt = 0; qt < 2; ++qt) {
            float t = lp[qt] + lscr[(wave * 2 + qt) * 64 + lane];
            t += __shfl_xor(t, 16, 64);
            t += __shfl_xor(t, 32, 64);
            lp[qt] = 1.f / t;
        }
#pragma unroll
        for (int dt = 0; dt < 4; ++dt)
#pragma unroll
            for (int qt = 0; qt < 2; ++qt) {
                f16x4 ov = {(f16_t)(o[dt][qt][0] * lp[qt]),
                            (f16_t)(o[dt][qt][1] * lp[qt]),
                            (f16_t)(o[dt][qt][2] * lp[qt]),
                            (f16_t)(o[dt][qt][3] * lp[qt])};
                int qrow = qrow0 + qt * 16 + l16;
                *(f16x4*)&ao[(size_t)qrow * D_MODEL + head * 64 + dt * 16 +
                             quad * 4] = ov;
            }
    }
}

extern "C" void kernel_launch(void* const* d_in, const int* in_sizes, int n_in,
                              void* d_out, int out_size, void* d_ws, size_t ws_size,
                              hipStream_t stream) {
    const float* x  = (const float*)d_in[0];
    const float* Wq = (const float*)d_in[1];
    const float* Wk = (const float*)d_in[2];
    const float* Wv = (const float*)d_in[3];
    const float* Wo = (const float*)d_in[4];

    f16_t* xb = (f16_t*)d_ws;                        // [4096][1024]
    f16_t* wq = xb + (size_t)LSEQ * D_MODEL;         // [3072][1024] qkv concat
    f16_t* wo = wq + (size_t)3 * D_MODEL * D_MODEL;  // [1024][1024]
    f16_t* qh = wo + (size_t)D_MODEL * D_MODEL;      // [16][4096][64]
    f16_t* kh = qh + (size_t)LSEQ * D_MODEL;
    f16_t* vh = kh + (size_t)LSEQ * D_MODEL;
    f16_t* v4 = vh + (size_t)LSEQ * D_MODEL;         // fragmented V
    f16_t* ao = v4 + (size_t)LSEQ * D_MODEL;         // [4096][1024]

    const int nx = LSEQ * D_MODEL;
    cvt_x<<<nx / 1024, 256, 0, stream>>>(x, xb, nx);
    cvt_w4<<<dim3(D_MODEL * D_MODEL / 1024, 4), 256, 0, stream>>>(Wq, Wk, Wv, Wo, wq);

    gemm_f16<<<dim3(LSEQ / 128, 3 * D_MODEL / 128), 256, 0, stream>>>(
        xb, wq, qh, LSEQ, 3 * D_MODEL, D_MODEL, 0);

    transpose_v<<<dim3(LSEQ / 64, NH), 256, 0, stream>>>(vh, v4);

    attn_kernel<<<dim3((LSEQ / 128) * NH), 512, 0, stream>>>(qh, kh, v4, ao);

    gemm_f16<<<dim3(LSEQ / 128, D_MODEL / 128), 256, 0, stream>>>(
        ao, wo, d_out, LSEQ, D_MODEL, D_MODEL, 1);
}